// Round 1
// baseline (19.084 us; speedup 1.0000x reference)
//
#include <hip/hip_runtime.h>

// out[i*1536 + j] = -(1/0.924458) * sum_{a,b} w[a][b] * x[3i+a][3j+b]
// x: 4608x4608 f32, w: 3x3 f32, out: 1536*1536 f32.
// Each thread computes 4 consecutive output columns (one float4 store),
// reading 3 rows x 12 contiguous floats (3x float4 loads per row).

__global__ __launch_bounds__(256) void conv3x3_s3_kernel(
    const float* __restrict__ x,
    const float* __restrict__ w,
    float* __restrict__ out)
{
    constexpr int W   = 4608;       // input row stride (floats)
    constexpr int NH  = 1536;       // output cols
    constexpr int JQ  = NH / 4;     // 384 quads per output row

    const int tid = blockIdx.x * blockDim.x + threadIdx.x;
    const int i   = tid / JQ;       // output row [0, 1536)
    const int jq  = tid - i * JQ;   // quad index [0, 384)

    // 3x3 weights: uniform-address loads, L1-broadcast across lanes.
    const float w00 = w[0], w01 = w[1], w02 = w[2];
    const float w10 = w[3], w11 = w[4], w12 = w[5];
    const float w20 = w[6], w21 = w[7], w22 = w[8];

    const float* base = x + (size_t)(3 * i) * W + 12 * jq;

    float acc0 = 0.f, acc1 = 0.f, acc2 = 0.f, acc3 = 0.f;

    #pragma unroll
    for (int a = 0; a < 3; ++a) {
        const float4* p = reinterpret_cast<const float4*>(base + (size_t)a * W);
        const float4 v0 = p[0];
        const float4 v1 = p[1];
        const float4 v2 = p[2];

        float wa0, wa1, wa2;
        if (a == 0)      { wa0 = w00; wa1 = w01; wa2 = w02; }
        else if (a == 1) { wa0 = w10; wa1 = w11; wa2 = w12; }
        else             { wa0 = w20; wa1 = w21; wa2 = w22; }

        // columns 0..11 of this row feed outputs j = 4jq .. 4jq+3
        acc0 += wa0 * v0.x + wa1 * v0.y + wa2 * v0.z;
        acc1 += wa0 * v0.w + wa1 * v1.x + wa2 * v1.y;
        acc2 += wa0 * v1.z + wa1 * v1.w + wa2 * v2.x;
        acc3 += wa0 * v2.y + wa1 * v2.z + wa2 * v2.w;
    }

    const float scale = -1.0f / 0.924458f;

    float4 r;
    r.x = acc0 * scale;
    r.y = acc1 * scale;
    r.z = acc2 * scale;
    r.w = acc3 * scale;

    float4* o = reinterpret_cast<float4*>(out + (size_t)i * NH + 4 * jq);
    *o = r;
}

extern "C" void kernel_launch(void* const* d_in, const int* in_sizes, int n_in,
                              void* d_out, int out_size, void* d_ws, size_t ws_size,
                              hipStream_t stream)
{
    const float* x = (const float*)d_in[0];   // 4608*4608
    const float* w = (const float*)d_in[1];   // 9
    float* out = (float*)d_out;               // 1536*1536

    constexpr int NW = 1536, JQ = 1536 / 4;
    const int total   = NW * JQ;              // 589824 threads
    const int block   = 256;
    const int grid    = total / block;        // 2304 blocks, exact

    conv3x3_s3_kernel<<<grid, block, 0, stream>>>(x, w, out);
}